// Round 29
// baseline (169.256 us; speedup 1.0000x reference)
//
#include <hip/hip_runtime.h>

// SpatialShiftConvBlock (B=8,T=64,N=21,C=128,F=256), ALL float32:
//   xs[b,t,n,c] = x[b,t,(n - c%21) mod 21, c]       (per-channel circular roll)
//   y  = xs @ W + b                                 (1x1 conv == GEMM K=128)
//   y  = (y - mean)*rsqrt(var + 1e-3)*gamma + beta  (BN training stats over B,T,N)
//   out = relu(y)                                   (float32 output)
//
// R28 realization: output dtype is FLOAT32 (reference returns jnp.float32;
// "(bf16)" in the test label is static generated text; threshold = 2% rel).
// 16 rounds of bf16 u16 writes half-filled the f32 buffer -> absmax always
// = refmax = 5.15625, which I misread as "writes never land".

#define NPOS 21
#define CIN 128
#define FOUT 256
#define BT 512            // B*T
#define M_TOTAL 10752     // BT*NPOS
#define BN_EPS 1e-3f

// K1: one block per (b,t) slab. The 21x128 slab is staged raw in LDS with
// fully-coalesced f32 loads; the circular shift is applied at read time as a
// same-address broadcast (conflict-free). Thread t owns output channel f=t:
// 21 fp32 accumulators over c=0..127; W row read coalesced across threads.
// Writes pre-norm y (f32) to d_out: 21 coalesced 1KB rows per block.
__global__ __launch_bounds__(256) void k_conv(const float* __restrict__ x,
                                              const float* __restrict__ W,
                                              const float* __restrict__ bias,
                                              float* __restrict__ y) {
    __shared__ float xsRaw[NPOS * CIN];       // 10.5 KB
    const int bt = blockIdx.x;
    const int t = threadIdx.x;
    const float* xin = x + (size_t)bt * (NPOS * CIN);
    for (int i = t; i < NPOS * CIN; i += 256) xsRaw[i] = xin[i];
    __syncthreads();

    const int f = t;
    float acc[NPOS];
    #pragma unroll
    for (int n = 0; n < NPOS; n++) acc[n] = 0.0f;

    int s = 0;                                // s = c % 21, kept incrementally
    for (int c = 0; c < CIN; c++) {
        float wv = W[c * FOUT + f];           // coalesced across threads
        int idx = NPOS - s; if (idx == NPOS) idx = 0;   // (0 - s) mod 21
        #pragma unroll
        for (int n = 0; n < NPOS; n++) {      // xs[n][c] = raw[(n-s) mod 21][c]
            acc[n] = fmaf(xsRaw[idx * CIN + c], wv, acc[n]);
            idx++; if (idx == NPOS) idx = 0;
        }
        s++; if (s == NPOS) s = 0;
    }
    const float bv = bias[f];
    float* yout = y + (size_t)bt * (NPOS * FOUT);
    #pragma unroll
    for (int n = 0; n < NPOS; n++)
        yout[n * FOUT + f] = acc[n] + bv;
}

// K2: one block per channel f. Reads column f of y (M_TOTAL f32, cached in
// registers: 42/thread), block-reduces sum/sumsq in LDS, then normalizes +
// ReLU in place. No workspace, no cross-block communication.
__global__ __launch_bounds__(256) void k_bn(float* __restrict__ y,
                                            const float* __restrict__ gamma,
                                            const float* __restrict__ beta) {
    const int f = blockIdx.x;
    const int t = threadIdx.x;
    float vals[M_TOTAL / 256];                // 42 per thread
    float sum = 0.0f, sq = 0.0f;
    for (int j = 0; j < M_TOTAL / 256; j++) {
        int m = j * 256 + t;
        float v = y[(size_t)m * FOUT + f];
        vals[j] = v; sum += v; sq += v * v;
    }
    __shared__ float rs[256], rq[256];
    __shared__ float sSc, sBs;
    rs[t] = sum; rq[t] = sq;
    __syncthreads();
    for (int off = 128; off > 0; off >>= 1) {
        if (t < off) { rs[t] += rs[t + off]; rq[t] += rq[t + off]; }
        __syncthreads();
    }
    if (t == 0) {
        const float invM = 1.0f / (float)M_TOTAL;
        float mean = rs[0] * invM;
        float var  = rq[0] * invM - mean * mean;
        float sc = rsqrtf(var + BN_EPS) * gamma[f];
        sSc = sc;
        sBs = beta[f] - mean * sc;
    }
    __syncthreads();
    const float sc = sSc, bs = sBs;
    for (int j = 0; j < M_TOTAL / 256; j++) {
        int m = j * 256 + t;
        float o = vals[j] * sc + bs;
        y[(size_t)m * FOUT + f] = fmaxf(o, 0.0f);
    }
}

// Template-named symbol kept defined (harness-compat; not launched).
extern "C" __global__ void SpatialShiftConvBlock_71923522339050_kernel() {}

extern "C" void kernel_launch(void* const* d_in, const int* in_sizes, int n_in,
                              void* d_out, int out_size, void* d_ws, size_t ws_size,
                              hipStream_t stream) {
    float* y = (float*)d_out;                 // FLOAT32 output
    k_conv<<<BT, 256, 0, stream>>>((const float*)d_in[0], (const float*)d_in[1],
                                   (const float*)d_in[2], y);
    k_bn<<<FOUT, 256, 0, stream>>>(y, (const float*)d_in[3], (const float*)d_in[4]);
}